// Round 1
// baseline (447.359 us; speedup 1.0000x reference)
//
#include <hip/hip_runtime.h>

#define VOCAB 4096
#define NROWS 65536          // B*L = 4*16384
#define DECAYF 0.99f
#define EPSF 1e-5f

// ---------------- ws layout (in floats) ----------------
// [0,      16384)  packed embed float4 (e0,e1,e2,e2sum)  (4096*4)
// [16384,  20480)  counts (4096)
// [20480,  32768)  weight sums (4096*3)
// [32768,  32770)  err accumulator (double)
// [32770,  32772)  n accumulator (double)

__global__ __launch_bounds__(256) void prep_kernel(const float* __restrict__ embed,
                                                   float4* __restrict__ pack) {
    #pragma clang fp contract(off)
    int v = blockIdx.x * 256 + threadIdx.x;
    if (v >= VOCAB) return;
    float e0 = embed[v * 3 + 0];
    float e1 = embed[v * 3 + 1];
    float e2 = embed[v * 3 + 2];
    // replicate numpy: sum(embed*embed, axis=1) = (e0^2 + e1^2) + e2^2, each product rounded
    float e2s = (e0 * e0 + e1 * e1) + e2 * e2;
    pack[v] = make_float4(e0, e1, e2, e2s);
}

__global__ __launch_bounds__(256) void vq_main_kernel(
    const float* __restrict__ feats,
    const float* __restrict__ embed,
    const float4* __restrict__ pack,
    float* __restrict__ quant_out,
    float* __restrict__ idx_out,
    float* __restrict__ cnt,
    float* __restrict__ wsum,
    double* __restrict__ err_acc) {
    #pragma clang fp contract(off)
    const int tid = threadIdx.x;
    const int wave = tid >> 6;
    const int lane = tid & 63;
    const int row = blockIdx.x * 64 + lane;

    const float f0 = feats[row * 3 + 0];
    const float f1 = feats[row * 3 + 1];
    const float f2 = feats[row * 3 + 2];
    // numpy: sum(flat*flat, axis=1) = (f0^2 + f1^2) + f2^2
    const float fsum = (f0 * f0 + f1 * f1) + f2 * f2;

    float best = INFINITY;
    int bidx = 0;
    const int v0 = wave * (VOCAB / 4);

    #pragma unroll 4
    for (int j = 0; j < VOCAB / 4; ++j) {
        const int v = v0 + j;
        const float4 p = pack[v];
        // BLAS-style dot: fma chain ascending in k, first product plain-rounded
        float dot = fmaf(p.z, f2, fmaf(p.y, f1, p.x * f0));
        // dist = (fsum - 2*dot) + e2sum   (2*dot exact; rounding order matches ref)
        float dist = (fsum - 2.0f * dot) + p.w;
        if (dist < best) { best = dist; bidx = v; }   // strict <: first index wins ties
    }

    __shared__ float sB[4][64];
    __shared__ int   sI[4][64];
    sB[wave][lane] = best;
    sI[wave][lane] = bidx;
    __syncthreads();

    if (tid < 64) {
        // merge waves in ascending order -> lowest index wins on exact ties
        for (int w = 1; w < 4; ++w) {
            float b = sB[w][lane];
            int   i = sI[w][lane];
            if (b < best) { best = b; bidx = i; }
        }
        idx_out[row] = (float)bidx;
        const float q0 = embed[bidx * 3 + 0];
        const float q1 = embed[bidx * 3 + 1];
        const float q2 = embed[bidx * 3 + 2];
        quant_out[row * 3 + 0] = q0;
        quant_out[row * 3 + 1] = q1;
        quant_out[row * 3 + 2] = q2;

        const float d0 = q0 - f0, d1 = q1 - f1, d2 = q2 - f2;
        float err = d0 * d0 + d1 * d1 + d2 * d2;
        #pragma unroll
        for (int off = 32; off >= 1; off >>= 1) err += __shfl_xor(err, off);
        if (lane == 0) atomicAdd(err_acc, (double)err);

        atomicAdd(&cnt[bidx], 1.0f);
        atomicAdd(&wsum[bidx * 3 + 0], f0);
        atomicAdd(&wsum[bidx * 3 + 1], f1);
        atomicAdd(&wsum[bidx * 3 + 2], f2);
    }
}

__global__ __launch_bounds__(256) void ema_kernel(
    const float* __restrict__ ema_cs,
    const float* __restrict__ ema_w,
    const float* __restrict__ cnt,
    const float* __restrict__ wsum,
    float* __restrict__ ncs_out,
    float* __restrict__ nw_out,
    double* __restrict__ n_acc) {
    int v = blockIdx.x * 256 + threadIdx.x;
    if (v >= VOCAB) return;
    float ncs = DECAYF * ema_cs[v] + (1.0f - DECAYF) * cnt[v];
    ncs_out[v] = ncs;
    nw_out[v * 3 + 0] = DECAYF * ema_w[v * 3 + 0] + (1.0f - DECAYF) * wsum[v * 3 + 0];
    nw_out[v * 3 + 1] = DECAYF * ema_w[v * 3 + 1] + (1.0f - DECAYF) * wsum[v * 3 + 1];
    nw_out[v * 3 + 2] = DECAYF * ema_w[v * 3 + 2] + (1.0f - DECAYF) * wsum[v * 3 + 2];

    float s = ncs;
    #pragma unroll
    for (int off = 32; off >= 1; off >>= 1) s += __shfl_xor(s, off);
    if ((threadIdx.x & 63) == 0) atomicAdd(n_acc, (double)s);
}

__global__ __launch_bounds__(256) void final_kernel(
    const float* __restrict__ ncs,
    const float* __restrict__ nw,
    const double* __restrict__ n_acc,
    const double* __restrict__ err_acc,
    float* __restrict__ embed_out,
    float* __restrict__ loss_out) {
    int v = blockIdx.x * 256 + threadIdx.x;
    if (v >= VOCAB) return;
    const float n = (float)(*n_acc);
    const float cs = (ncs[v] + EPSF) / (n + (float)VOCAB * EPSF) * n;
    const float d0 = nw[v * 3 + 0] / cs;
    const float d1 = nw[v * 3 + 1] / cs;
    const float d2 = nw[v * 3 + 2] / cs;
    const float nrm = fmaxf(sqrtf(d1 * d1 + d2 * d2), EPSF);
    embed_out[v * 3 + 0] = d0;
    embed_out[v * 3 + 1] = d1 / nrm;
    embed_out[v * 3 + 2] = d2 / nrm;
    if (v == 0) {
        loss_out[0] = (float)(1.25 * (*err_acc) / (double)(NROWS * 3));
    }
}

extern "C" void kernel_launch(void* const* d_in, const int* in_sizes, int n_in,
                              void* d_out, int out_size, void* d_ws, size_t ws_size,
                              hipStream_t stream) {
    const float* feats  = (const float*)d_in[0];   // 65536*3
    const float* embed  = (const float*)d_in[1];   // 4096*3
    const float* ema_cs = (const float*)d_in[2];   // 4096
    const float* ema_w  = (const float*)d_in[3];   // 4096*3

    float* out = (float*)d_out;
    float* quant_out = out;                         // 196608
    float* idx_out   = out + 196608;                // 65536
    float* loss_out  = out + 262144;                // 1
    float* embed_out = out + 262145;                // 12288
    float* ncs_out   = out + 274433;                // 4096
    float* nw_out    = out + 278529;                // 12288

    float* ws = (float*)d_ws;
    float4* pack   = (float4*)ws;                   // 16384 floats
    float*  cnt    = ws + 16384;                    // 4096
    float*  wsum   = ws + 20480;                    // 12288
    double* err_ac = (double*)(ws + 32768);
    double* n_ac   = (double*)(ws + 32770);

    // zero accumulators (counts + wsum + err + n): floats [16384, 32772)
    hipMemsetAsync(ws + 16384, 0, (32772 - 16384) * sizeof(float), stream);

    prep_kernel<<<VOCAB / 256, 256, 0, stream>>>(embed, pack);
    vq_main_kernel<<<NROWS / 64, 256, 0, stream>>>(feats, embed, pack,
                                                   quant_out, idx_out, cnt, wsum, err_ac);
    ema_kernel<<<VOCAB / 256, 256, 0, stream>>>(ema_cs, ema_w, cnt, wsum,
                                                ncs_out, nw_out, n_ac);
    final_kernel<<<VOCAB / 256, 256, 0, stream>>>(ncs_out, nw_out, n_ac, err_ac,
                                                  embed_out, loss_out);
}

// Round 2
// 393.062 us; speedup vs baseline: 1.1381x; 1.1381x over previous
//
#include <hip/hip_runtime.h>
#include <math.h>

#define VOCAB 4096
#define NROWS 65536          // B*L = 4*16384
#define DECAYF 0.99f
#define EPSF 1e-5f

// ---------------- ws layout (in floats) ----------------
// [0,      16384)  packed embed float4 (-2e0,-2e1,-2e2,e2sum)  (4096*4)
// [16384,  20480)  counts (4096)
// [20480,  32768)  weight sums (4096*3)
// [32768,  32770)  err accumulator (double)
// [32770,  32772)  n accumulator (double)

__global__ __launch_bounds__(256) void prep_kernel(const float* __restrict__ embed,
                                                   float4* __restrict__ pack) {
    #pragma clang fp contract(off)
    int v = blockIdx.x * 256 + threadIdx.x;
    if (v >= VOCAB) return;
    float e0 = embed[v * 3 + 0];
    float e1 = embed[v * 3 + 1];
    float e2 = embed[v * 3 + 2];
    // numpy: sum(embed*embed, axis=1) = (e0^2 + e1^2) + e2^2 (each product rounded)
    float e2s = (e0 * e0 + e1 * e1) + e2 * e2;
    // store -2*e (exact power-of-2 scaling) so the scan is 1 mul + 2 fma + 2 add
    pack[v] = make_float4(-2.0f * e0, -2.0f * e1, -2.0f * e2, e2s);
}

// 512 threads = 8 waves. Each wave scans a 512-candidate slice of the LDS
// table; each lane owns 4 rows. Log-tree merge across waves, index tie-break.
__global__ __launch_bounds__(512) void vq_main_kernel(
    const float* __restrict__ feats,
    const float4* __restrict__ pack,
    float* __restrict__ quant_out,
    float* __restrict__ idx_out,
    float* __restrict__ cnt,
    float* __restrict__ wsum,
    double* __restrict__ err_acc) {
    #pragma clang fp contract(off)
    __shared__ float4 tab[VOCAB];          // 64 KB
    // merge scratch aliases the table region (only used after scan completes)
    float4* mB4 = tab;                     // [4][64] best  (4 KB)
    int4*   mI4 = (int4*)(tab + 256);      // [4][64] index (4 KB)

    const int tid  = threadIdx.x;
    const int wave = tid >> 6;
    const int lane = tid & 63;

    // stage table: 4096 float4 over 512 threads (coalesced, conflict-free)
    #pragma unroll
    for (int k = 0; k < 8; ++k)
        tab[tid + k * 512] = pack[tid + k * 512];

    // load this lane's 4 rows (48 B contiguous = 3x float4)
    const int rbase = blockIdx.x * 256 + lane * 4;
    const float4 fa = *(const float4*)(feats + rbase * 3);
    const float4 fb = *(const float4*)(feats + rbase * 3 + 4);
    const float4 fc = *(const float4*)(feats + rbase * 3 + 8);
    float f0[4] = {fa.x, fa.w, fb.z, fc.y};
    float f1[4] = {fa.y, fb.x, fb.w, fc.z};
    float f2[4] = {fa.z, fb.y, fc.x, fc.w};
    float fs[4];
    #pragma unroll
    for (int r = 0; r < 4; ++r)
        fs[r] = (f0[r] * f0[r] + f1[r] * f1[r]) + f2[r] * f2[r];

    __syncthreads();

    float best[4] = {INFINITY, INFINITY, INFINITY, INFINITY};
    int   bidx[4] = {0, 0, 0, 0};
    const int v0 = wave * 512;

    #pragma unroll 4
    for (int j = 0; j < 512; ++j) {
        const float4 p = tab[v0 + j];      // broadcast ds_read_b128
        const int v = v0 + j;
        #pragma unroll
        for (int r = 0; r < 4; ++r) {
            // t = -2*dot, rounding bit-identical to fmaf(e2,f2,fmaf(e1,f1,e0*f0))
            float t = fmaf(p.z, f2[r], fmaf(p.y, f1[r], p.x * f0[r]));
            float dist = (fs[r] + t) + p.w;   // == (fsum - 2*dot) + e2sum
            if (dist < best[r]) { best[r] = dist; bidx[r] = v; }  // strict <
        }
    }

    __syncthreads();   // all waves done reading tab -> scratch may alias it

    // ---- merge level 1: 8 -> 4 ----
    if (wave >= 4) {
        mB4[(wave - 4) * 64 + lane] = make_float4(best[0], best[1], best[2], best[3]);
        mI4[(wave - 4) * 64 + lane] = make_int4(bidx[0], bidx[1], bidx[2], bidx[3]);
    }
    __syncthreads();
    if (wave < 4) {
        float4 b = mB4[wave * 64 + lane];
        int4   i = mI4[wave * 64 + lane];
        float bb[4] = {b.x, b.y, b.z, b.w};
        int   ii[4] = {i.x, i.y, i.z, i.w};
        #pragma unroll
        for (int r = 0; r < 4; ++r)
            if (bb[r] < best[r] || (bb[r] == best[r] && ii[r] < bidx[r])) {
                best[r] = bb[r]; bidx[r] = ii[r];
            }
    }
    __syncthreads();
    // ---- merge level 2: 4 -> 2 ----
    if (wave == 2 || wave == 3) {
        mB4[(wave - 2) * 64 + lane] = make_float4(best[0], best[1], best[2], best[3]);
        mI4[(wave - 2) * 64 + lane] = make_int4(bidx[0], bidx[1], bidx[2], bidx[3]);
    }
    __syncthreads();
    if (wave < 2) {
        float4 b = mB4[wave * 64 + lane];
        int4   i = mI4[wave * 64 + lane];
        float bb[4] = {b.x, b.y, b.z, b.w};
        int   ii[4] = {i.x, i.y, i.z, i.w};
        #pragma unroll
        for (int r = 0; r < 4; ++r)
            if (bb[r] < best[r] || (bb[r] == best[r] && ii[r] < bidx[r])) {
                best[r] = bb[r]; bidx[r] = ii[r];
            }
    }
    __syncthreads();
    // ---- merge level 3: 2 -> 1 ----
    if (wave == 1) {
        mB4[lane] = make_float4(best[0], best[1], best[2], best[3]);
        mI4[lane] = make_int4(bidx[0], bidx[1], bidx[2], bidx[3]);
    }
    __syncthreads();
    if (wave == 0) {
        float4 b = mB4[lane];
        int4   i = mI4[lane];
        float bb[4] = {b.x, b.y, b.z, b.w};
        int   ii[4] = {i.x, i.y, i.z, i.w};
        #pragma unroll
        for (int r = 0; r < 4; ++r)
            if (bb[r] < best[r] || (bb[r] == best[r] && ii[r] < bidx[r])) {
                best[r] = bb[r]; bidx[r] = ii[r];
            }

        // ---- epilogue (wave 0 only): gather, write, accumulate ----
        float q0[4], q1[4], q2[4];
        float err = 0.0f;
        #pragma unroll
        for (int r = 0; r < 4; ++r) {
            float4 p = pack[bidx[r]];              // global (L2-resident)
            q0[r] = -0.5f * p.x;                   // exact recovery of e
            q1[r] = -0.5f * p.y;
            q2[r] = -0.5f * p.z;
            float d0 = q0[r] - f0[r], d1 = q1[r] - f1[r], d2 = q2[r] - f2[r];
            err += d0 * d0 + d1 * d1 + d2 * d2;
        }
        *(float4*)(idx_out + rbase) =
            make_float4((float)bidx[0], (float)bidx[1], (float)bidx[2], (float)bidx[3]);
        *(float4*)(quant_out + rbase * 3) =
            make_float4(q0[0], q1[0], q2[0], q0[1]);
        *(float4*)(quant_out + rbase * 3 + 4) =
            make_float4(q1[1], q2[1], q0[2], q1[2]);
        *(float4*)(quant_out + rbase * 3 + 8) =
            make_float4(q2[2], q0[3], q1[3], q2[3]);
        #pragma unroll
        for (int r = 0; r < 4; ++r) {
            atomicAdd(&cnt[bidx[r]], 1.0f);
            atomicAdd(&wsum[bidx[r] * 3 + 0], f0[r]);
            atomicAdd(&wsum[bidx[r] * 3 + 1], f1[r]);
            atomicAdd(&wsum[bidx[r] * 3 + 2], f2[r]);
        }
        #pragma unroll
        for (int off = 32; off >= 1; off >>= 1) err += __shfl_xor(err, off);
        if (lane == 0) atomicAdd(err_acc, (double)err);
    }
}

__global__ __launch_bounds__(256) void ema_kernel(
    const float* __restrict__ ema_cs,
    const float* __restrict__ ema_w,
    const float* __restrict__ cnt,
    const float* __restrict__ wsum,
    float* __restrict__ ncs_out,
    float* __restrict__ nw_out,
    double* __restrict__ n_acc) {
    int v = blockIdx.x * 256 + threadIdx.x;
    if (v >= VOCAB) return;
    float ncs = DECAYF * ema_cs[v] + (1.0f - DECAYF) * cnt[v];
    ncs_out[v] = ncs;
    nw_out[v * 3 + 0] = DECAYF * ema_w[v * 3 + 0] + (1.0f - DECAYF) * wsum[v * 3 + 0];
    nw_out[v * 3 + 1] = DECAYF * ema_w[v * 3 + 1] + (1.0f - DECAYF) * wsum[v * 3 + 1];
    nw_out[v * 3 + 2] = DECAYF * ema_w[v * 3 + 2] + (1.0f - DECAYF) * wsum[v * 3 + 2];

    float s = ncs;
    #pragma unroll
    for (int off = 32; off >= 1; off >>= 1) s += __shfl_xor(s, off);
    if ((threadIdx.x & 63) == 0) atomicAdd(n_acc, (double)s);
}

__global__ __launch_bounds__(256) void final_kernel(
    const float* __restrict__ ncs,
    const float* __restrict__ nw,
    const double* __restrict__ n_acc,
    const double* __restrict__ err_acc,
    float* __restrict__ embed_out,
    float* __restrict__ loss_out) {
    int v = blockIdx.x * 256 + threadIdx.x;
    if (v >= VOCAB) return;
    const float n = (float)(*n_acc);
    const float cs = (ncs[v] + EPSF) / (n + (float)VOCAB * EPSF) * n;
    const float d0 = nw[v * 3 + 0] / cs;
    const float d1 = nw[v * 3 + 1] / cs;
    const float d2 = nw[v * 3 + 2] / cs;
    const float nrm = fmaxf(sqrtf(d1 * d1 + d2 * d2), EPSF);
    embed_out[v * 3 + 0] = d0;
    embed_out[v * 3 + 1] = d1 / nrm;
    embed_out[v * 3 + 2] = d2 / nrm;
    if (v == 0) {
        loss_out[0] = (float)(1.25 * (*err_acc) / (double)(NROWS * 3));
    }
}

extern "C" void kernel_launch(void* const* d_in, const int* in_sizes, int n_in,
                              void* d_out, int out_size, void* d_ws, size_t ws_size,
                              hipStream_t stream) {
    const float* feats  = (const float*)d_in[0];   // 65536*3
    const float* embed  = (const float*)d_in[1];   // 4096*3
    const float* ema_cs = (const float*)d_in[2];   // 4096
    const float* ema_w  = (const float*)d_in[3];   // 4096*3

    float* out = (float*)d_out;
    float* quant_out = out;                         // 196608
    float* idx_out   = out + 196608;                // 65536
    float* loss_out  = out + 262144;                // 1
    float* embed_out = out + 262145;                // 12288
    float* ncs_out   = out + 274433;                // 4096
    float* nw_out    = out + 278529;                // 12288

    float* ws = (float*)d_ws;
    float4* pack   = (float4*)ws;                   // 16384 floats
    float*  cnt    = ws + 16384;                    // 4096
    float*  wsum   = ws + 20480;                    // 12288
    double* err_ac = (double*)(ws + 32768);
    double* n_ac   = (double*)(ws + 32770);

    // zero accumulators (counts + wsum + err + n): floats [16384, 32772)
    hipMemsetAsync(ws + 16384, 0, (32772 - 16384) * sizeof(float), stream);

    prep_kernel<<<VOCAB / 256, 256, 0, stream>>>(embed, pack);
    vq_main_kernel<<<NROWS / 256, 512, 0, stream>>>(feats, pack,
                                                    quant_out, idx_out, cnt, wsum, err_ac);
    ema_kernel<<<VOCAB / 256, 256, 0, stream>>>(ema_cs, ema_w, cnt, wsum,
                                                ncs_out, nw_out, n_ac);
    final_kernel<<<VOCAB / 256, 256, 0, stream>>>(ncs_out, nw_out, n_ac, err_ac,
                                                  embed_out, loss_out);
}